// Round 6
// baseline (554.466 us; speedup 1.0000x reference)
//
#include <hip/hip_runtime.h>
#include <cstdint>
#include <cmath>

#define B_ 2
#define S_ 2048
#define D_ 2048
#define H_ 16
#define HD_ 128

#define NEG_SENTINEL -1.0e30f

typedef __bf16 bf16;
typedef __attribute__((ext_vector_type(4))) __bf16 bf16x4;
typedef __attribute__((ext_vector_type(8))) __bf16 bf16x8;
typedef __attribute__((ext_vector_type(4))) float f32x4;

__device__ __forceinline__ void gload_lds16(const void* g, void* l) {
  __builtin_amdgcn_global_load_lds(
      (const __attribute__((address_space(1))) unsigned int*)g,
      (__attribute__((address_space(3))) unsigned int*)l, 16, 0, 0);
}

__device__ __forceinline__ f32x4 mfma16(bf16x8 a, bf16x8 b, f32x4 c) {
  return __builtin_amdgcn_mfma_f32_16x16x32_bf16(a, b, c, 0, 0, 0);
}

// ---------------------------------------------------------------------------
// fp32 -> bf16 convert. One thread = 4 elements. (fallback path)
// ---------------------------------------------------------------------------
__global__ __launch_bounds__(256) void cvt_f32_bf16(
    const float* __restrict__ in, bf16* __restrict__ out)
{
  int i = blockIdx.x * 256 + threadIdx.x;
  f32x4 v = ((const f32x4*)in)[i];
  bf16x4 o;
#pragma unroll
  for (int j = 0; j < 4; ++j) o[j] = (bf16)v[j];
  ((bf16x4*)out)[i] = o;
}

// ---------------------------------------------------------------------------
// Fused front-end convert: x (8192 blocks) + Wq/Wk/Wv (4096 blocks each)
// in ONE launch. Wo excluded (its slot aliases Wv until QKV GEMM is done).
// ---------------------------------------------------------------------------
__global__ __launch_bounds__(256) void cvt_qkvx(
    const float* __restrict__ x, bf16* __restrict__ xb,
    const float* __restrict__ wq, const float* __restrict__ wk,
    const float* __restrict__ wv, bf16* __restrict__ wout)
{
  int b = (int)blockIdx.x;
  const float* in; bf16* out; int base;
  if (b < 8192)      { in = x;  out = xb; base = b; }
  else {
    int r = b - 8192; int j = r >> 12; base = r & 4095;
    if (j == 0)      { in = wq; out = wout; }
    else if (j == 1) { in = wk; out = wout + 4194304; }
    else             { in = wv; out = wout + 8388608; }
  }
  int i = base * 256 + threadIdx.x;
  f32x4 v = ((const f32x4*)in)[i];
  bf16x4 o;
#pragma unroll
  for (int t2 = 0; t2 < 4; ++t2) o[t2] = (bf16)v[t2];
  ((bf16x4*)out)[i] = o;
}

// ---------------------------------------------------------------------------
// GEMM (verified, ~897 TF): 128x128 tile, BK=64.
// R1-R4 post-mortem: 256-class pipelined tiles hit 1109 TF intrinsic but
// grid quantization eats the gain; legacy balanced grids win end-to-end.
// ---------------------------------------------------------------------------
#define GTM 128
#define GTN 128
#define GBK 64

template <typename OT>
__global__ __launch_bounds__(256) void gemm_xwt(
    const bf16* __restrict__ A, const bf16* __restrict__ W, OT* __restrict__ C,
    int M, int N, int K, int ldc)
{
  __shared__ bf16 sA[GTM * GBK];
  __shared__ bf16 sB[GTN * GBK];
  const int tid  = threadIdx.x;
  const int wave = tid >> 6, lane = tid & 63;
  const int quad = lane >> 4, l16 = lane & 15;
  const int tm = blockIdx.y * GTM;
  const int tn = blockIdx.x * GTN;
  const int wm = (wave >> 1) * 64, wn = (wave & 1) * 64;

  f32x4 acc[4][4];
#pragma unroll
  for (int i = 0; i < 4; ++i)
#pragma unroll
    for (int j = 0; j < 4; ++j) acc[i][j] = (f32x4)0.0f;

  for (int k0 = 0; k0 < K; k0 += GBK) {
    __syncthreads();
#pragma unroll
    for (int g = 0; g < 4; ++g) {
      int gb  = (g * 4 + wave) * 64;
      int p   = gb + lane;
      int row = p >> 3, pos = p & 7;
      int cc  = pos ^ (row & 7);
      gload_lds16(A + (size_t)(tm + row) * K + k0 + cc * 8, (char*)sA + (size_t)gb * 16);
      gload_lds16(W + (size_t)(tn + row) * K + k0 + cc * 8, (char*)sB + (size_t)gb * 16);
    }
    __syncthreads();

#pragma unroll
    for (int t = 0; t < 2; ++t) {
      bf16x8 af[4], bfr[4];
#pragma unroll
      for (int i = 0; i < 4; ++i) {
        int rowa = wm + i * 16 + l16;
        int posa = (t * 4 + quad) ^ (rowa & 7);
        af[i] = *(const bf16x8*)(sA + rowa * GBK + posa * 8);
        int rowb = wn + i * 16 + l16;
        int posb = (t * 4 + quad) ^ (rowb & 7);
        bfr[i] = *(const bf16x8*)(sB + rowb * GBK + posb * 8);
      }
#pragma unroll
      for (int i = 0; i < 4; ++i)
#pragma unroll
        for (int j = 0; j < 4; ++j)
          acc[i][j] = mfma16(af[i], bfr[j], acc[i][j]);
    }
  }

#pragma unroll
  for (int i = 0; i < 4; ++i)
#pragma unroll
    for (int r = 0; r < 4; ++r) {
      int row = tm + wm + i * 16 + quad * 4 + r;
#pragma unroll
      for (int j = 0; j < 4; ++j) {
        int col = tn + wn + j * 16 + l16;
        C[(size_t)row * ldc + col] = (OT)acc[i][j][r];
      }
    }
}

// ---------------------------------------------------------------------------
// RoPE in-place; Q pre-scaled by 1/sqrt(HD)*log2(e). Row stride rs.
// ---------------------------------------------------------------------------
__global__ __launch_bounds__(256) void rope_qk(
    bf16* __restrict__ Q, bf16* __restrict__ Kk,
    const float* __restrict__ cosT, const float* __restrict__ sinT, int rs)
{
  const float kappa = 0.08838834764831845f * 1.4426950408889634f;
  int t = blockIdx.x * 256 + threadIdx.x;
  int d = t & 63;
  int h = (t >> 6) & (H_ - 1);
  int s = (t >> 10) & (S_ - 1);
  int b = t >> 21;
  size_t base = ((size_t)(b * S_ + s)) * rs + (size_t)h * HD_;
  float c1 = cosT[s * HD_ + d];
  float s1 = sinT[s * HD_ + d];
  float c2 = cosT[s * HD_ + d + 64];
  float s2 = sinT[s * HD_ + d + 64];
  {
    float x1 = (float)Q[base + d], x2 = (float)Q[base + d + 64];
    Q[base + d]      = (bf16)((x1 * c1 - x2 * s1) * kappa);
    Q[base + d + 64] = (bf16)((x2 * c2 + x1 * s2) * kappa);
  }
  {
    float x1 = (float)Kk[base + d], x2 = (float)Kk[base + d + 64];
    Kk[base + d]      = (bf16)(x1 * c1 - x2 * s1);
    Kk[base + d + 64] = (bf16)(x2 * c2 + x1 * s2);
  }
}

// ---------------------------------------------------------------------------
// V transpose: V[b][s][...] (row stride rs) -> Vt[(b*H+h)*128+d][s].
// ---------------------------------------------------------------------------
__global__ __launch_bounds__(256) void transpose_v(
    const bf16* __restrict__ V, bf16* __restrict__ Vt, int rs)
{
  __shared__ bf16 sT[64 * 72];
  const int tid = threadIdx.x;
  const int si = blockIdx.x;
  const int di = blockIdx.y;
  const int bh = blockIdx.z;
  const int b  = bh >> 4, h = bh & 15;

  const bf16* src = V + (size_t)b * S_ * rs + (size_t)h * HD_ + di * 64;
  bf16*       dst = Vt + ((size_t)bh * HD_ + di * 64) * S_ + si * 64;

#pragma unroll
  for (int half = 0; half < 2; ++half) {
    int r  = half * 32 + (tid >> 3);
    int c0 = (tid & 7) * 8;
    bf16x8 v = *(const bf16x8*)(src + (size_t)(si * 64 + r) * rs + c0);
    *(bf16x8*)(sT + r * 72 + c0) = v;
  }
  __syncthreads();
#pragma unroll
  for (int half = 0; half < 2; ++half) {
    int dr = half * 32 + (tid >> 3);
    int c0 = (tid & 7) * 8;
    bf16x8 o;
#pragma unroll
    for (int j = 0; j < 8; ++j) o[j] = sT[(c0 + j) * 72 + dr];
    *(bf16x8*)(dst + (size_t)dr * S_ + c0) = o;
  }
}

// ---------------------------------------------------------------------------
// Flash attention fwd, causal. R6: NO K/V LDS staging — fragments are read
// directly from global (L2-resident by construction: XCD swizzle pins each
// head-column to one XCD; 4 cols x (K+V = 1MB) = 4MB = per-XCD L2).
// R5 post-mortem: LDS dbuf cost occupancy (3->2 blocks/CU) and regressed;
// the guide's m169 lesson says don't stage L2-fit data at all. Addresses
// below are the XOR-swizzle-unwound equivalents of the staged path:
//   kf[t]  = K [kk0+jt*16+l16][(t*4+quad)*8 ..+7]   (16 rows x 64B / instr)
//   vf     = Vt[jd*16+l16][kk0+(ks*4+quad)*8 ..+7]
// -> byte-identical operand values, so numerics are unchanged.
// LDS = sP only (9KB, wave-private; same-wave LDS RAW needs no barrier).
// No barriers, no vmcnt drains; ~4 blocks/CU.
// ---------------------------------------------------------------------------
#define ABK 64
#define SPS 72

__global__ __launch_bounds__(256) void attn_fwd(
    const bf16* __restrict__ Q, const bf16* __restrict__ K,
    const bf16* __restrict__ Vt, bf16* __restrict__ O, int rs)
{
  __shared__ bf16 sP[64 * SPS];      // 9 KB

  const int tid  = threadIdx.x;
  const int wave = tid >> 6, lane = tid & 63;
  const int quad = lane >> 4, l16 = lane & 15;

  const int lin   = (int)blockIdx.x;
  const int low3  = lin & 7;
  const int rest  = lin >> 3;
  const int pairx = rest & 15;
  const int colhi = rest >> 4;
  const int col   = low3 + (colhi << 3);
  const int b = col >> 4, h = col & 15;

  const bf16* Qh  = Q + (size_t)b * S_ * rs + (size_t)h * HD_;
  const bf16* Kh  = K + (size_t)b * S_ * rs + (size_t)h * HD_;
  const bf16* Vth = Vt + ((size_t)(b * H_ + h) * HD_) * S_;
  bf16*       Oh  = O + (size_t)b * S_ * D_ + (size_t)h * HD_;

  const int wq = wave * 16;

#pragma unroll 1
  for (int seg = 0; seg < 2; ++seg) {
    const int qt = seg == 0 ? pairx : 31 - pairx;
    const int q0 = qt * 64;
    const int wq_abs = q0 + wq;

    bf16x8 qf[4];
    {
      const bf16* rp = Qh + (size_t)(wq_abs + l16) * rs + quad * 8;
#pragma unroll
      for (int t = 0; t < 4; ++t) qf[t] = *(const bf16x8*)(rp + t * 32);
    }

    f32x4 o_acc[8];
#pragma unroll
    for (int j = 0; j < 8; ++j) o_acc[j] = (f32x4)0.0f;
    float m_col = NEG_SENTINEL;
    float l_col = 0.0f;

    const int nkt = qt + 1;
#pragma unroll 1
    for (int kt = 0; kt < nkt; ++kt) {
      const int kk0 = kt * ABK;

      // ---- S^T = K Q^T, K fragments straight from global (L2) ----
      f32x4 st[4];
#pragma unroll
      for (int jt = 0; jt < 4; ++jt) {
        const bf16* krow = Kh + (size_t)(kk0 + jt * 16 + l16) * rs;
        bf16x8 kf[4];
#pragma unroll
        for (int t = 0; t < 4; ++t)
          kf[t] = *(const bf16x8*)(krow + (t * 4 + quad) * 8);
        f32x4 a2 = (f32x4)0.0f;
#pragma unroll
        for (int t = 0; t < 4; ++t) a2 = mfma16(kf[t], qf[t], a2);
        st[jt] = a2;
      }

      if (kk0 + 63 > wq_abs) {
        int qcol = wq_abs + l16;
#pragma unroll
        for (int jt = 0; jt < 4; ++jt)
#pragma unroll
          for (int r = 0; r < 4; ++r) {
            int key = kk0 + jt * 16 + quad * 4 + r;
            if (key > qcol) st[jt][r] = NEG_SENTINEL;
          }
      }

      float mx = NEG_SENTINEL;
#pragma unroll
      for (int jt = 0; jt < 4; ++jt)
#pragma unroll
        for (int r = 0; r < 4; ++r) mx = fmaxf(mx, st[jt][r]);
      mx = fmaxf(mx, __shfl_xor(mx, 16, 64));
      mx = fmaxf(mx, __shfl_xor(mx, 32, 64));
      float m_new = fmaxf(m_col, mx);
      float alpha = exp2f(m_col - m_new);
      float ts = 0.0f;
#pragma unroll
      for (int jt = 0; jt < 4; ++jt) {
        bf16x4 pk;
#pragma unroll
        for (int r = 0; r < 4; ++r) {
          float p = exp2f(st[jt][r] - m_new);
          ts += p;
          pk[r] = (bf16)p;
        }
        *(bf16x4*)(sP + (wq + l16) * SPS + jt * 16 + quad * 4) = pk;
      }
      ts += __shfl_xor(ts, 16, 64);
      ts += __shfl_xor(ts, 32, 64);
      l_col = l_col * alpha + ts;
      m_col = m_new;
#pragma unroll
      for (int r = 0; r < 4; ++r) {
        float av = __shfl(alpha, quad * 4 + r, 64);
#pragma unroll
        for (int jd = 0; jd < 8; ++jd) o_acc[jd][r] *= av;
      }
      // sP rows are wave-private: same-wave LDS RAW needs no barrier.

      // ---- O += P V, V^T fragments straight from global (L2/L1) ----
#pragma unroll
      for (int ks = 0; ks < 2; ++ks) {
        bf16x8 pf = *(const bf16x8*)(sP + (wq + l16) * SPS + ks * 32 + quad * 8);
#pragma unroll
        for (int jd = 0; jd < 8; ++jd) {
          const bf16* vrow = Vth + (size_t)(jd * 16 + l16) * S_ + kk0;
          bf16x8 vf = *(const bf16x8*)(vrow + (ks * 4 + quad) * 8);
          o_acc[jd] = mfma16(pf, vf, o_acc[jd]);
        }
      }
    }

#pragma unroll
    for (int r = 0; r < 4; ++r) {
      float lv = __shfl(l_col, quad * 4 + r, 64);
      float inv_l = 1.0f / lv;
      int row = wq_abs + quad * 4 + r;
#pragma unroll
      for (int jd = 0; jd < 8; ++jd) {
        int colo = jd * 16 + l16;
        Oh[(size_t)row * D_ + colo] = (bf16)(o_acc[jd][r] * inv_l);
      }
    }
  }
}

// ---------------------------------------------------------------------------
extern "C" void kernel_launch(void* const* d_in, const int* in_sizes, int n_in,
                              void* d_out, int out_size, void* d_ws, size_t ws_size,
                              hipStream_t stream) {
  const float* x    = (const float*)d_in[0];
  const float* Wq   = (const float*)d_in[1];
  const float* Wk   = (const float*)d_in[2];
  const float* Wv   = (const float*)d_in[3];
  const float* Wo   = (const float*)d_in[4];
  const float* cosT = (const float*)d_in[5];
  const float* sinT = (const float*)d_in[6];
  float* out = (float*)d_out;

  const size_t NE = (size_t)B_ * S_ * D_;   // 8,388,608
  const size_t WE = (size_t)D_ * D_;        // 4,194,304
  const int M = B_ * S_;
  const int cvtX = (int)(NE / 1024);
  const int cvtW = (int)(WE / 1024);

  if (ws_size >= (size_t)92274688) {
    // ---- fused-QKV path (88 MB): QKV(48) | xb(16) | Wqkv->ctx+Wo_b(24) ----
    bf16* QKV   = (bf16*)d_ws;              // (4096, 6144) row-major
    bf16* xb    = QKV + (size_t)M * 6144;
    bf16* Wqkv  = xb + NE;
    bf16* ctx   = Wqkv;                     // reuse after QKV GEMM
    bf16* Wob   = Wqkv + 2 * WE;
    bf16* Vt    = xb;                       // reuse after QKV GEMM

    // fused cvt: x + Wq + Wk + Wv in one launch (Wo later: aliases Wv slot)
    cvt_qkvx<<<8192 + 3 * 4096, 256, 0, stream>>>(x, xb, Wq, Wk, Wv, Wqkv);
    gemm_xwt<bf16><<<dim3(48, 32), 256, 0, stream>>>(xb, Wqkv, QKV, M, 3 * D_, D_, 3 * D_);
    rope_qk<<<(B_ * S_ * H_ * 64) / 256, 256, 0, stream>>>(QKV, QKV + D_, cosT, sinT, 3 * D_);
    transpose_v<<<dim3(32, 2, 32), 256, 0, stream>>>(QKV + 2 * D_, Vt, 3 * D_);
    attn_fwd<<<512, 256, 0, stream>>>(QKV, QKV + D_, Vt, ctx, 3 * D_);
    cvt_f32_bf16<<<cvtW, 256, 0, stream>>>(Wo, Wob);
    gemm_xwt<float><<<dim3(16, 32), 256, 0, stream>>>(ctx, Wob, out, M, D_, D_, D_);
  } else {
    // ---- fallback (72 MB): separate GEMMs, same attn ----
    bf16* Qb    = (bf16*)d_ws;
    bf16* Kb    = Qb + NE;
    bf16* Vb    = Kb + NE;
    bf16* Cb    = Vb + NE;                  // bf16(x) -> later Vt
    bf16* Wslot = Cb + NE;

    cvt_f32_bf16<<<cvtX, 256, 0, stream>>>(x, Cb);
    cvt_f32_bf16<<<cvtW, 256, 0, stream>>>(Wq, Wslot);
    gemm_xwt<bf16><<<dim3(16, 32), 256, 0, stream>>>(Cb, Wslot, Qb, M, D_, D_, D_);
    cvt_f32_bf16<<<cvtW, 256, 0, stream>>>(Wk, Wslot);
    gemm_xwt<bf16><<<dim3(16, 32), 256, 0, stream>>>(Cb, Wslot, Kb, M, D_, D_, D_);
    cvt_f32_bf16<<<cvtW, 256, 0, stream>>>(Wv, Wslot);
    gemm_xwt<bf16><<<dim3(16, 32), 256, 0, stream>>>(Cb, Wslot, Vb, M, D_, D_, D_);
    rope_qk<<<(B_ * S_ * H_ * 64) / 256, 256, 0, stream>>>(Qb, Kb, cosT, sinT, D_);
    transpose_v<<<dim3(32, 2, 32), 256, 0, stream>>>(Vb, Cb, D_);
    attn_fwd<<<512, 256, 0, stream>>>(Qb, Kb, Cb, Vb, D_);
    cvt_f32_bf16<<<cvtW, 256, 0, stream>>>(Wo, Wslot);
    gemm_xwt<float><<<dim3(16, 32), 256, 0, stream>>>(Vb, Wslot, out, M, D_, D_, D_);
  }
}

// Round 7
// 414.558 us; speedup vs baseline: 1.3375x; 1.3375x over previous
//
#include <hip/hip_runtime.h>
#include <cstdint>
#include <cmath>

#define B_ 2
#define S_ 2048
#define D_ 2048
#define H_ 16
#define HD_ 128

#define NEG_SENTINEL -1.0e30f

typedef __bf16 bf16;
typedef __attribute__((ext_vector_type(4))) __bf16 bf16x4;
typedef __attribute__((ext_vector_type(8))) __bf16 bf16x8;
typedef __attribute__((ext_vector_type(4))) float f32x4;

__device__ __forceinline__ void gload_lds16(const void* g, void* l) {
  __builtin_amdgcn_global_load_lds(
      (const __attribute__((address_space(1))) unsigned int*)g,
      (__attribute__((address_space(3))) unsigned int*)l, 16, 0, 0);
}

__device__ __forceinline__ f32x4 mfma16(bf16x8 a, bf16x8 b, f32x4 c) {
  return __builtin_amdgcn_mfma_f32_16x16x32_bf16(a, b, c, 0, 0, 0);
}

// ---------------------------------------------------------------------------
// fp32 -> bf16 convert. One thread = 4 elements. (fallback path)
// ---------------------------------------------------------------------------
__global__ __launch_bounds__(256) void cvt_f32_bf16(
    const float* __restrict__ in, bf16* __restrict__ out)
{
  int i = blockIdx.x * 256 + threadIdx.x;
  f32x4 v = ((const f32x4*)in)[i];
  bf16x4 o;
#pragma unroll
  for (int j = 0; j < 4; ++j) o[j] = (bf16)v[j];
  ((bf16x4*)out)[i] = o;
}

// ---------------------------------------------------------------------------
// Fused front-end convert: x (8192 blocks) + Wq/Wk/Wv (4096 blocks each)
// in ONE launch. Wo excluded (its slot aliases Wv until QKV GEMM is done).
// ---------------------------------------------------------------------------
__global__ __launch_bounds__(256) void cvt_qkvx(
    const float* __restrict__ x, bf16* __restrict__ xb,
    const float* __restrict__ wq, const float* __restrict__ wk,
    const float* __restrict__ wv, bf16* __restrict__ wout)
{
  int b = (int)blockIdx.x;
  const float* in; bf16* out; int base;
  if (b < 8192)      { in = x;  out = xb; base = b; }
  else {
    int r = b - 8192; int j = r >> 12; base = r & 4095;
    if (j == 0)      { in = wq; out = wout; }
    else if (j == 1) { in = wk; out = wout + 4194304; }
    else             { in = wv; out = wout + 8388608; }
  }
  int i = base * 256 + threadIdx.x;
  f32x4 v = ((const f32x4*)in)[i];
  bf16x4 o;
#pragma unroll
  for (int t2 = 0; t2 < 4; ++t2) o[t2] = (bf16)v[t2];
  ((bf16x4*)out)[i] = o;
}

// ---------------------------------------------------------------------------
// GEMM (verified, ~897 TF): 128x128 tile, BK=64.
// R1-R4 post-mortem: 256-class pipelined tiles hit 1109 TF intrinsic but
// grid quantization eats the gain; legacy balanced grids win end-to-end.
// ---------------------------------------------------------------------------
#define GTM 128
#define GTN 128
#define GBK 64

template <typename OT>
__global__ __launch_bounds__(256) void gemm_xwt(
    const bf16* __restrict__ A, const bf16* __restrict__ W, OT* __restrict__ C,
    int M, int N, int K, int ldc)
{
  __shared__ bf16 sA[GTM * GBK];
  __shared__ bf16 sB[GTN * GBK];
  const int tid  = threadIdx.x;
  const int wave = tid >> 6, lane = tid & 63;
  const int quad = lane >> 4, l16 = lane & 15;
  const int tm = blockIdx.y * GTM;
  const int tn = blockIdx.x * GTN;
  const int wm = (wave >> 1) * 64, wn = (wave & 1) * 64;

  f32x4 acc[4][4];
#pragma unroll
  for (int i = 0; i < 4; ++i)
#pragma unroll
    for (int j = 0; j < 4; ++j) acc[i][j] = (f32x4)0.0f;

  for (int k0 = 0; k0 < K; k0 += GBK) {
    __syncthreads();
#pragma unroll
    for (int g = 0; g < 4; ++g) {
      int gb  = (g * 4 + wave) * 64;
      int p   = gb + lane;
      int row = p >> 3, pos = p & 7;
      int cc  = pos ^ (row & 7);
      gload_lds16(A + (size_t)(tm + row) * K + k0 + cc * 8, (char*)sA + (size_t)gb * 16);
      gload_lds16(W + (size_t)(tn + row) * K + k0 + cc * 8, (char*)sB + (size_t)gb * 16);
    }
    __syncthreads();

#pragma unroll
    for (int t = 0; t < 2; ++t) {
      bf16x8 af[4], bfr[4];
#pragma unroll
      for (int i = 0; i < 4; ++i) {
        int rowa = wm + i * 16 + l16;
        int posa = (t * 4 + quad) ^ (rowa & 7);
        af[i] = *(const bf16x8*)(sA + rowa * GBK + posa * 8);
        int rowb = wn + i * 16 + l16;
        int posb = (t * 4 + quad) ^ (rowb & 7);
        bfr[i] = *(const bf16x8*)(sB + rowb * GBK + posb * 8);
      }
#pragma unroll
      for (int i = 0; i < 4; ++i)
#pragma unroll
        for (int j = 0; j < 4; ++j)
          acc[i][j] = mfma16(af[i], bfr[j], acc[i][j]);
    }
  }

#pragma unroll
  for (int i = 0; i < 4; ++i)
#pragma unroll
    for (int r = 0; r < 4; ++r) {
      int row = tm + wm + i * 16 + quad * 4 + r;
#pragma unroll
      for (int j = 0; j < 4; ++j) {
        int col = tn + wn + j * 16 + l16;
        C[(size_t)row * ldc + col] = (OT)acc[i][j][r];
      }
    }
}

// ---------------------------------------------------------------------------
// RoPE in-place; Q pre-scaled by 1/sqrt(HD)*log2(e). Row stride rs.
// ---------------------------------------------------------------------------
__global__ __launch_bounds__(256) void rope_qk(
    bf16* __restrict__ Q, bf16* __restrict__ Kk,
    const float* __restrict__ cosT, const float* __restrict__ sinT, int rs)
{
  const float kappa = 0.08838834764831845f * 1.4426950408889634f;
  int t = blockIdx.x * 256 + threadIdx.x;
  int d = t & 63;
  int h = (t >> 6) & (H_ - 1);
  int s = (t >> 10) & (S_ - 1);
  int b = t >> 21;
  size_t base = ((size_t)(b * S_ + s)) * rs + (size_t)h * HD_;
  float c1 = cosT[s * HD_ + d];
  float s1 = sinT[s * HD_ + d];
  float c2 = cosT[s * HD_ + d + 64];
  float s2 = sinT[s * HD_ + d + 64];
  {
    float x1 = (float)Q[base + d], x2 = (float)Q[base + d + 64];
    Q[base + d]      = (bf16)((x1 * c1 - x2 * s1) * kappa);
    Q[base + d + 64] = (bf16)((x2 * c2 + x1 * s2) * kappa);
  }
  {
    float x1 = (float)Kk[base + d], x2 = (float)Kk[base + d + 64];
    Kk[base + d]      = (bf16)(x1 * c1 - x2 * s1);
    Kk[base + d + 64] = (bf16)(x2 * c2 + x1 * s2);
  }
}

// ---------------------------------------------------------------------------
// V transpose: V[b][s][...] (row stride rs) -> Vt[(b*H+h)*128+d][s].
// ---------------------------------------------------------------------------
__global__ __launch_bounds__(256) void transpose_v(
    const bf16* __restrict__ V, bf16* __restrict__ Vt, int rs)
{
  __shared__ bf16 sT[64 * 72];
  const int tid = threadIdx.x;
  const int si = blockIdx.x;
  const int di = blockIdx.y;
  const int bh = blockIdx.z;
  const int b  = bh >> 4, h = bh & 15;

  const bf16* src = V + (size_t)b * S_ * rs + (size_t)h * HD_ + di * 64;
  bf16*       dst = Vt + ((size_t)bh * HD_ + di * 64) * S_ + si * 64;

#pragma unroll
  for (int half = 0; half < 2; ++half) {
    int r  = half * 32 + (tid >> 3);
    int c0 = (tid & 7) * 8;
    bf16x8 v = *(const bf16x8*)(src + (size_t)(si * 64 + r) * rs + c0);
    *(bf16x8*)(sT + r * 72 + c0) = v;
  }
  __syncthreads();
#pragma unroll
  for (int half = 0; half < 2; ++half) {
    int dr = half * 32 + (tid >> 3);
    int c0 = (tid & 7) * 8;
    bf16x8 o;
#pragma unroll
    for (int j = 0; j < 8; ++j) o[j] = sT[(c0 + j) * 72 + dr];
    *(bf16x8*)(dst + (size_t)dr * S_ + c0) = o;
  }
}

// ---------------------------------------------------------------------------
// Flash attention fwd, causal. R7: the verified R0 staged structure
// (single-buffer K/V in LDS via global_load_lds, 2 barriers/tile, S^T=K*Q^T
// softmax, wave-private sP, XCD-local head columns) with ONE change:
// grid 1024 = one q-tile per block (was 512 balanced pairs).
// R6 counters showed attn is latency-bound (MfmaUtil 5.5% unstaged; staged
// version's only latency hiding is cross-block TLP) and the 512-grid left
// residency at 2 blocks/CU while 41KB LDS allows 3. 1024 blocks -> 3
// resident + 1 queued per CU (12 waves vs 8).
// LPT dispatch: qt = 31 - (rest&31) -> longest blocks first, tail ~1 tile.
// col = low3 + colhi*8 unchanged -> same 4 head-columns per XCD (4MB L2).
// Per-block body is byte-identical to R0 -> same numerics.
// ---------------------------------------------------------------------------
#define ABK 64
#define SPS 72

__global__ __launch_bounds__(256) void attn_fwd(
    const bf16* __restrict__ Q, const bf16* __restrict__ K,
    const bf16* __restrict__ Vt, bf16* __restrict__ O, int rs)
{
  __shared__ bf16 sK[ABK * HD_];     // 16 KB
  __shared__ bf16 sVT[HD_ * ABK];    // 16 KB
  __shared__ bf16 sP[64 * SPS];      // 9 KB   (total 41 KB -> 3 blocks/CU)

  const int tid  = threadIdx.x;
  const int wave = tid >> 6, lane = tid & 63;
  const int quad = lane >> 4, l16 = lane & 15;

  // decode: 1024 = 8 (XCD) x 32 (qt, LPT-reversed) x 4 (colhi)
  const int lin   = (int)blockIdx.x;
  const int low3  = lin & 7;
  const int rest  = lin >> 3;          // 0..127
  const int qt    = 31 - (rest & 31);  // longest (qt=31) dispatched first
  const int colhi = rest >> 5;         // 0..3
  const int col   = low3 + (colhi << 3);
  const int b = col >> 4, h = col & 15;

  const bf16* Qh  = Q + (size_t)b * S_ * rs + (size_t)h * HD_;
  const bf16* Kh  = K + (size_t)b * S_ * rs + (size_t)h * HD_;
  const bf16* Vth = Vt + ((size_t)(b * H_ + h) * HD_) * S_;
  bf16*       Oh  = O + (size_t)b * S_ * D_ + (size_t)h * HD_;

  const int wq = wave * 16;
  const int q0 = qt * 64;
  const int wq_abs = q0 + wq;

  // Q fragments (B operand; layout [n=l16][k=quad*8+j])
  bf16x8 qf[4];
  {
    const bf16* rp = Qh + (size_t)(wq_abs + l16) * rs + quad * 8;
#pragma unroll
    for (int t = 0; t < 4; ++t) qf[t] = *(const bf16x8*)(rp + t * 32);
  }

  f32x4 o_acc[8];
#pragma unroll
  for (int j = 0; j < 8; ++j) o_acc[j] = (f32x4)0.0f;
  float m_col = NEG_SENTINEL;
  float l_col = 0.0f;

  const int nkt = qt + 1;
#pragma unroll 1
  for (int kt = 0; kt < nkt; ++kt) {
    const int kk0 = kt * ABK;
    __syncthreads();   // all waves done with sK/sVT before restage

    // stage K: 1024 chunks over 256 threads, pos = cc ^ (row&15)
#pragma unroll
    for (int g = 0; g < 4; ++g) {
      int p   = g * 256 + tid;
      int row = p >> 4, pos = p & 15;
      int cc  = pos ^ (row & 15);
      gload_lds16(Kh + (size_t)(kk0 + row) * rs + cc * 8, (char*)sK + (size_t)p * 16);
    }
    // stage V^T from Vt: 1024 chunks, pos = cc ^ (d&7)
#pragma unroll
    for (int g = 0; g < 4; ++g) {
      int p  = g * 256 + tid;
      int d  = p >> 3, pos = p & 7;
      int cc = pos ^ (d & 7);
      gload_lds16(Vth + (size_t)d * S_ + kk0 + cc * 8, (char*)sVT + (size_t)p * 16);
    }
    __syncthreads();   // drain global_load_lds

    // waves whose 16 q-rows are entirely below this key tile skip compute
    if (kk0 <= wq_abs + 15) {
      // S^T = K Q^T : lane holds key=(jt*16+quad*4+r), q-col=l16
      f32x4 st[4];
#pragma unroll
      for (int jt = 0; jt < 4; ++jt) {
        bf16x8 kf[4];
#pragma unroll
        for (int t = 0; t < 4; ++t) {
          int pos = (t * 4 + quad) ^ l16;
          kf[t] = *(const bf16x8*)(sK + (jt * 16 + l16) * HD_ + pos * 8);
        }
        f32x4 a2 = (f32x4)0.0f;
#pragma unroll
        for (int t = 0; t < 4; ++t) a2 = mfma16(kf[t], qf[t], a2);
        st[jt] = a2;
      }

      // causal mask only where the tile crosses this wave's diagonal
      if (kk0 + 63 > wq_abs) {
        int qcol = wq_abs + l16;
#pragma unroll
        for (int jt = 0; jt < 4; ++jt)
#pragma unroll
          for (int r = 0; r < 4; ++r) {
            int key = kk0 + jt * 16 + quad * 4 + r;
            if (key > qcol) st[jt][r] = NEG_SENTINEL;
          }
      }

      // online softmax (base-2): in-lane tree + 2 shuffles per reduction
      float mx = NEG_SENTINEL;
#pragma unroll
      for (int jt = 0; jt < 4; ++jt)
#pragma unroll
        for (int r = 0; r < 4; ++r) mx = fmaxf(mx, st[jt][r]);
      mx = fmaxf(mx, __shfl_xor(mx, 16, 64));
      mx = fmaxf(mx, __shfl_xor(mx, 32, 64));
      float m_new = fmaxf(m_col, mx);
      float alpha = exp2f(m_col - m_new);
      float ts = 0.0f;
#pragma unroll
      for (int jt = 0; jt < 4; ++jt) {
        bf16x4 pk;
#pragma unroll
        for (int r = 0; r < 4; ++r) {
          float p = exp2f(st[jt][r] - m_new);
          ts += p;
          pk[r] = (bf16)p;
        }
        *(bf16x4*)(sP + (wq + l16) * SPS + jt * 16 + quad * 4) = pk;
      }
      ts += __shfl_xor(ts, 16, 64);
      ts += __shfl_xor(ts, 32, 64);
      l_col = l_col * alpha + ts;
      m_col = m_new;
#pragma unroll
      for (int r = 0; r < 4; ++r) {
        float av = __shfl(alpha, quad * 4 + r, 64);
#pragma unroll
        for (int jd = 0; jd < 8; ++jd) o_acc[jd][r] *= av;
      }
      // sP rows are wave-private: same-wave LDS RAW needs no barrier.

      // O += P V  (two 32-key steps)
#pragma unroll
      for (int ks = 0; ks < 2; ++ks) {
        bf16x8 pf = *(const bf16x8*)(sP + (wq + l16) * SPS + ks * 32 + quad * 8);
#pragma unroll
        for (int jd = 0; jd < 8; ++jd) {
          int pos = (ks * 4 + quad) ^ (l16 & 7);
          bf16x8 vf = *(const bf16x8*)(sVT + (jd * 16 + l16) * ABK + pos * 8);
          o_acc[jd] = mfma16(pf, vf, o_acc[jd]);
        }
      }
    }
  }

  // epilogue: fetch denom from q-col lanes, store ctx (dense stride D_)
#pragma unroll
  for (int r = 0; r < 4; ++r) {
    float lv = __shfl(l_col, quad * 4 + r, 64);
    float inv_l = 1.0f / lv;
    int row = wq_abs + quad * 4 + r;
#pragma unroll
    for (int jd = 0; jd < 8; ++jd) {
      int colo = jd * 16 + l16;
      Oh[(size_t)row * D_ + colo] = (bf16)(o_acc[jd][r] * inv_l);
    }
  }
}

// ---------------------------------------------------------------------------
extern "C" void kernel_launch(void* const* d_in, const int* in_sizes, int n_in,
                              void* d_out, int out_size, void* d_ws, size_t ws_size,
                              hipStream_t stream) {
  const float* x    = (const float*)d_in[0];
  const float* Wq   = (const float*)d_in[1];
  const float* Wk   = (const float*)d_in[2];
  const float* Wv   = (const float*)d_in[3];
  const float* Wo   = (const float*)d_in[4];
  const float* cosT = (const float*)d_in[5];
  const float* sinT = (const float*)d_in[6];
  float* out = (float*)d_out;

  const size_t NE = (size_t)B_ * S_ * D_;   // 8,388,608
  const size_t WE = (size_t)D_ * D_;        // 4,194,304
  const int M = B_ * S_;
  const int cvtX = (int)(NE / 1024);
  const int cvtW = (int)(WE / 1024);

  if (ws_size >= (size_t)92274688) {
    // ---- fused-QKV path (88 MB): QKV(48) | xb(16) | Wqkv->ctx+Wo_b(24) ----
    bf16* QKV   = (bf16*)d_ws;              // (4096, 6144) row-major
    bf16* xb    = QKV + (size_t)M * 6144;
    bf16* Wqkv  = xb + NE;
    bf16* ctx   = Wqkv;                     // reuse after QKV GEMM
    bf16* Wob   = Wqkv + 2 * WE;
    bf16* Vt    = xb;                       // reuse after QKV GEMM

    // fused cvt: x + Wq + Wk + Wv in one launch (Wo later: aliases Wv slot)
    cvt_qkvx<<<8192 + 3 * 4096, 256, 0, stream>>>(x, xb, Wq, Wk, Wv, Wqkv);
    gemm_xwt<bf16><<<dim3(48, 32), 256, 0, stream>>>(xb, Wqkv, QKV, M, 3 * D_, D_, 3 * D_);
    rope_qk<<<(B_ * S_ * H_ * 64) / 256, 256, 0, stream>>>(QKV, QKV + D_, cosT, sinT, 3 * D_);
    transpose_v<<<dim3(32, 2, 32), 256, 0, stream>>>(QKV + 2 * D_, Vt, 3 * D_);
    attn_fwd<<<1024, 256, 0, stream>>>(QKV, QKV + D_, Vt, ctx, 3 * D_);
    cvt_f32_bf16<<<cvtW, 256, 0, stream>>>(Wo, Wob);
    gemm_xwt<float><<<dim3(16, 32), 256, 0, stream>>>(ctx, Wob, out, M, D_, D_, D_);
  } else {
    // ---- fallback (72 MB): separate GEMMs, same attn ----
    bf16* Qb    = (bf16*)d_ws;
    bf16* Kb    = Qb + NE;
    bf16* Vb    = Kb + NE;
    bf16* Cb    = Vb + NE;                  // bf16(x) -> later Vt
    bf16* Wslot = Cb + NE;

    cvt_f32_bf16<<<cvtX, 256, 0, stream>>>(x, Cb);
    cvt_f32_bf16<<<cvtW, 256, 0, stream>>>(Wq, Wslot);
    gemm_xwt<bf16><<<dim3(16, 32), 256, 0, stream>>>(Cb, Wslot, Qb, M, D_, D_, D_);
    cvt_f32_bf16<<<cvtW, 256, 0, stream>>>(Wk, Wslot);
    gemm_xwt<bf16><<<dim3(16, 32), 256, 0, stream>>>(Cb, Wslot, Kb, M, D_, D_, D_);
    cvt_f32_bf16<<<cvtW, 256, 0, stream>>>(Wv, Wslot);
    gemm_xwt<bf16><<<dim3(16, 32), 256, 0, stream>>>(Cb, Wslot, Vb, M, D_, D_, D_);
    rope_qk<<<(B_ * S_ * H_ * 64) / 256, 256, 0, stream>>>(Qb, Kb, cosT, sinT, D_);
    transpose_v<<<dim3(32, 2, 32), 256, 0, stream>>>(Vb, Cb, D_);
    attn_fwd<<<1024, 256, 0, stream>>>(Qb, Kb, Cb, Vb, D_);
    cvt_f32_bf16<<<cvtW, 256, 0, stream>>>(Wo, Wslot);
    gemm_xwt<float><<<dim3(16, 32), 256, 0, stream>>>(Vb, Wslot, out, M, D_, D_, D_);
  }
}

// Round 8
// 408.538 us; speedup vs baseline: 1.3572x; 1.0147x over previous
//
#include <hip/hip_runtime.h>
#include <cstdint>
#include <cmath>

#define B_ 2
#define S_ 2048
#define D_ 2048
#define H_ 16
#define HD_ 128

#define NEG_SENTINEL -1.0e30f

typedef __bf16 bf16;
typedef __attribute__((ext_vector_type(4))) __bf16 bf16x4;
typedef __attribute__((ext_vector_type(8))) __bf16 bf16x8;
typedef __attribute__((ext_vector_type(4))) float f32x4;

__device__ __forceinline__ void gload_lds16(const void* g, void* l) {
  __builtin_amdgcn_global_load_lds(
      (const __attribute__((address_space(1))) unsigned int*)g,
      (__attribute__((address_space(3))) unsigned int*)l, 16, 0, 0);
}

__device__ __forceinline__ f32x4 mfma16(bf16x8 a, bf16x8 b, f32x4 c) {
  return __builtin_amdgcn_mfma_f32_16x16x32_bf16(a, b, c, 0, 0, 0);
}

// ---------------------------------------------------------------------------
// fp32 -> bf16 convert. One thread = 4 elements. (fallback path)
// ---------------------------------------------------------------------------
__global__ __launch_bounds__(256) void cvt_f32_bf16(
    const float* __restrict__ in, bf16* __restrict__ out)
{
  int i = blockIdx.x * 256 + threadIdx.x;
  f32x4 v = ((const f32x4*)in)[i];
  bf16x4 o;
#pragma unroll
  for (int j = 0; j < 4; ++j) o[j] = (bf16)v[j];
  ((bf16x4*)out)[i] = o;
}

// ---------------------------------------------------------------------------
// Fused front-end convert: x (8192 blocks) + Wq/Wk/Wv (4096 blocks each)
// in ONE launch. Wo excluded (its slot aliases Wv until QKV GEMM is done).
// ---------------------------------------------------------------------------
__global__ __launch_bounds__(256) void cvt_qkvx(
    const float* __restrict__ x, bf16* __restrict__ xb,
    const float* __restrict__ wq, const float* __restrict__ wk,
    const float* __restrict__ wv, bf16* __restrict__ wout)
{
  int b = (int)blockIdx.x;
  const float* in; bf16* out; int base;
  if (b < 8192)      { in = x;  out = xb; base = b; }
  else {
    int r = b - 8192; int j = r >> 12; base = r & 4095;
    if (j == 0)      { in = wq; out = wout; }
    else if (j == 1) { in = wk; out = wout + 4194304; }
    else             { in = wv; out = wout + 8388608; }
  }
  int i = base * 256 + threadIdx.x;
  f32x4 v = ((const f32x4*)in)[i];
  bf16x4 o;
#pragma unroll
  for (int t2 = 0; t2 < 4; ++t2) o[t2] = (bf16)v[t2];
  ((bf16x4*)out)[i] = o;
}

// ---------------------------------------------------------------------------
// GEMM (verified, ~897 TF): 128x128 tile, BK=64.
// R1-R4 post-mortem: 256-class pipelined tiles hit 1109 TF intrinsic but
// grid quantization eats the gain; legacy balanced grids win end-to-end.
// ---------------------------------------------------------------------------
#define GTM 128
#define GTN 128
#define GBK 64

template <typename OT>
__global__ __launch_bounds__(256) void gemm_xwt(
    const bf16* __restrict__ A, const bf16* __restrict__ W, OT* __restrict__ C,
    int M, int N, int K, int ldc)
{
  __shared__ bf16 sA[GTM * GBK];
  __shared__ bf16 sB[GTN * GBK];
  const int tid  = threadIdx.x;
  const int wave = tid >> 6, lane = tid & 63;
  const int quad = lane >> 4, l16 = lane & 15;
  const int tm = blockIdx.y * GTM;
  const int tn = blockIdx.x * GTN;
  const int wm = (wave >> 1) * 64, wn = (wave & 1) * 64;

  f32x4 acc[4][4];
#pragma unroll
  for (int i = 0; i < 4; ++i)
#pragma unroll
    for (int j = 0; j < 4; ++j) acc[i][j] = (f32x4)0.0f;

  for (int k0 = 0; k0 < K; k0 += GBK) {
    __syncthreads();
#pragma unroll
    for (int g = 0; g < 4; ++g) {
      int gb  = (g * 4 + wave) * 64;
      int p   = gb + lane;
      int row = p >> 3, pos = p & 7;
      int cc  = pos ^ (row & 7);
      gload_lds16(A + (size_t)(tm + row) * K + k0 + cc * 8, (char*)sA + (size_t)gb * 16);
      gload_lds16(W + (size_t)(tn + row) * K + k0 + cc * 8, (char*)sB + (size_t)gb * 16);
    }
    __syncthreads();

#pragma unroll
    for (int t = 0; t < 2; ++t) {
      bf16x8 af[4], bfr[4];
#pragma unroll
      for (int i = 0; i < 4; ++i) {
        int rowa = wm + i * 16 + l16;
        int posa = (t * 4 + quad) ^ (rowa & 7);
        af[i] = *(const bf16x8*)(sA + rowa * GBK + posa * 8);
        int rowb = wn + i * 16 + l16;
        int posb = (t * 4 + quad) ^ (rowb & 7);
        bfr[i] = *(const bf16x8*)(sB + rowb * GBK + posb * 8);
      }
#pragma unroll
      for (int i = 0; i < 4; ++i)
#pragma unroll
        for (int j = 0; j < 4; ++j)
          acc[i][j] = mfma16(af[i], bfr[j], acc[i][j]);
    }
  }

#pragma unroll
  for (int i = 0; i < 4; ++i)
#pragma unroll
    for (int r = 0; r < 4; ++r) {
      int row = tm + wm + i * 16 + quad * 4 + r;
#pragma unroll
      for (int j = 0; j < 4; ++j) {
        int col = tn + wn + j * 16 + l16;
        C[(size_t)row * ldc + col] = (OT)acc[i][j][r];
      }
    }
}

// ---------------------------------------------------------------------------
// RoPE in-place, VECTORIZED (R8): one thread = 8 paired lanes (16 bf16).
// Same per-element math and rounding as the scalar version -> bit-identical.
// Q pre-scaled by 1/sqrt(HD)*log2(e). Row stride rs.
// ---------------------------------------------------------------------------
__global__ __launch_bounds__(256) void rope_qk(
    bf16* __restrict__ Q, bf16* __restrict__ Kk,
    const float* __restrict__ cosT, const float* __restrict__ sinT, int rs)
{
  const float kappa = 0.08838834764831845f * 1.4426950408889634f;
  int t  = blockIdx.x * 256 + threadIdx.x;     // B*S*H*8 threads
  int d0 = (t & 7) * 8;
  int h  = (t >> 3) & (H_ - 1);
  int s  = (t >> 7) & (S_ - 1);
  int b  = t >> 18;
  size_t base = ((size_t)(b * S_ + s)) * rs + (size_t)h * HD_;

  const float* cl = cosT + s * HD_ + d0;
  const float* sl = sinT + s * HD_ + d0;

  bf16x8 ql = *(const bf16x8*)(Q + base + d0);
  bf16x8 qh = *(const bf16x8*)(Q + base + 64 + d0);
  bf16x8 kl = *(const bf16x8*)(Kk + base + d0);
  bf16x8 kh = *(const bf16x8*)(Kk + base + 64 + d0);

  bf16x8 qlo, qho, klo, kho;
#pragma unroll
  for (int i = 0; i < 8; ++i) {
    float c1 = cl[i], s1 = sl[i];
    float c2 = cl[64 + i], s2 = sl[64 + i];
    float x1 = (float)ql[i], x2 = (float)qh[i];
    qlo[i] = (bf16)((x1 * c1 - x2 * s1) * kappa);
    qho[i] = (bf16)((x2 * c2 + x1 * s2) * kappa);
    float y1 = (float)kl[i], y2 = (float)kh[i];
    klo[i] = (bf16)(y1 * c1 - y2 * s1);
    kho[i] = (bf16)(y2 * c2 + y1 * s2);
  }
  *(bf16x8*)(Q + base + d0)       = qlo;
  *(bf16x8*)(Q + base + 64 + d0)  = qho;
  *(bf16x8*)(Kk + base + d0)      = klo;
  *(bf16x8*)(Kk + base + 64 + d0) = kho;
}

// ---------------------------------------------------------------------------
// V transpose: V[b][s][...] (row stride rs) -> Vt[(b*H+h)*128+d][s].
// ---------------------------------------------------------------------------
__global__ __launch_bounds__(256) void transpose_v(
    const bf16* __restrict__ V, bf16* __restrict__ Vt, int rs)
{
  __shared__ bf16 sT[64 * 72];
  const int tid = threadIdx.x;
  const int si = blockIdx.x;
  const int di = blockIdx.y;
  const int bh = blockIdx.z;
  const int b  = bh >> 4, h = bh & 15;

  const bf16* src = V + (size_t)b * S_ * rs + (size_t)h * HD_ + di * 64;
  bf16*       dst = Vt + ((size_t)bh * HD_ + di * 64) * S_ + si * 64;

#pragma unroll
  for (int half = 0; half < 2; ++half) {
    int r  = half * 32 + (tid >> 3);
    int c0 = (tid & 7) * 8;
    bf16x8 v = *(const bf16x8*)(src + (size_t)(si * 64 + r) * rs + c0);
    *(bf16x8*)(sT + r * 72 + c0) = v;
  }
  __syncthreads();
#pragma unroll
  for (int half = 0; half < 2; ++half) {
    int dr = half * 32 + (tid >> 3);
    int c0 = (tid & 7) * 8;
    bf16x8 o;
#pragma unroll
    for (int j = 0; j < 8; ++j) o[j] = sT[(c0 + j) * 72 + dr];
    *(bf16x8*)(dst + (size_t)dr * S_ + c0) = o;
  }
}

// ---------------------------------------------------------------------------
// Flash attention fwd, causal. R8: 8-WAVE blocks (128 q-rows / block).
// R7 counters (MfmaUtil 12.9, VALUBusy 35.8, both pipes idle >50%):
// latency-bound; each 32KB staged tile fed only 4 waves and residency was
// 12 waves/CU. With 128 q-rows: (a) stage traffic HALVES (each tile feeds
// 8 waves; sum tiles/col 528 -> 272); (b) residency = 2 blocks x 8 waves =
// 16 waves/CU (VGPR 92 allows exactly 16; LDS 50KB x 2 = 100KB <= 160).
// MFMA/VALU totals unchanged (causal area invariant); per-wave body is
// byte-identical to R7 -> same numerics.
// Grid 512 = 8 XCD x 16 qt (LPT-reversed) x 4 colhi; 4 head-cols per XCD
// keeps the K/V working set at 4MB = per-XCD L2.
// ---------------------------------------------------------------------------
#define ABK 64
#define SPS 72

__global__ __launch_bounds__(512) void attn_fwd(
    const bf16* __restrict__ Q, const bf16* __restrict__ K,
    const bf16* __restrict__ Vt, bf16* __restrict__ O, int rs)
{
  __shared__ bf16 sK[ABK * HD_];      // 16 KB
  __shared__ bf16 sVT[HD_ * ABK];     // 16 KB
  __shared__ bf16 sP[128 * SPS];      // 18 KB   (total 50 KB -> 2 blocks/CU)

  const int tid  = threadIdx.x;
  const int wave = tid >> 6, lane = tid & 63;
  const int quad = lane >> 4, l16 = lane & 15;

  // decode: 512 = 8 (XCD) x 16 (qt, LPT-reversed) x 4 (colhi)
  const int lin   = (int)blockIdx.x;
  const int low3  = lin & 7;
  const int rest  = lin >> 3;          // 0..63
  const int qt    = 15 - (rest & 15);  // longest (qt=15) dispatched first
  const int colhi = rest >> 4;         // 0..3
  const int col   = low3 + (colhi << 3);
  const int b = col >> 4, h = col & 15;

  const bf16* Qh  = Q + (size_t)b * S_ * rs + (size_t)h * HD_;
  const bf16* Kh  = K + (size_t)b * S_ * rs + (size_t)h * HD_;
  const bf16* Vth = Vt + ((size_t)(b * H_ + h) * HD_) * S_;
  bf16*       Oh  = O + (size_t)b * S_ * D_ + (size_t)h * HD_;

  const int wq = wave * 16;            // 0..112
  const int q0 = qt * 128;
  const int wq_abs = q0 + wq;

  // Q fragments (B operand; layout [n=l16][k=quad*8+j])
  bf16x8 qf[4];
  {
    const bf16* rp = Qh + (size_t)(wq_abs + l16) * rs + quad * 8;
#pragma unroll
    for (int t = 0; t < 4; ++t) qf[t] = *(const bf16x8*)(rp + t * 32);
  }

  f32x4 o_acc[8];
#pragma unroll
  for (int j = 0; j < 8; ++j) o_acc[j] = (f32x4)0.0f;
  float m_col = NEG_SENTINEL;
  float l_col = 0.0f;

  const int nkt = 2 * qt + 2;          // k-tiles covering q rows q0..q0+127
#pragma unroll 1
  for (int kt = 0; kt < nkt; ++kt) {
    const int kk0 = kt * ABK;
    __syncthreads();   // all waves done with sK/sVT before restage

    // stage K: 1024 chunks over 512 threads, pos = cc ^ (row&15)
#pragma unroll
    for (int g = 0; g < 2; ++g) {
      int p   = g * 512 + tid;
      int row = p >> 4, pos = p & 15;
      int cc  = pos ^ (row & 15);
      gload_lds16(Kh + (size_t)(kk0 + row) * rs + cc * 8, (char*)sK + (size_t)p * 16);
    }
    // stage V^T from Vt: 1024 chunks, pos = cc ^ (d&7)
#pragma unroll
    for (int g = 0; g < 2; ++g) {
      int p  = g * 512 + tid;
      int d  = p >> 3, pos = p & 7;
      int cc = pos ^ (d & 7);
      gload_lds16(Vth + (size_t)d * S_ + kk0 + cc * 8, (char*)sVT + (size_t)p * 16);
    }
    __syncthreads();   // drain global_load_lds

    // waves whose 16 q-rows are entirely below this key tile skip compute
    if (kk0 <= wq_abs + 15) {
      // S^T = K Q^T : lane holds key=(jt*16+quad*4+r), q-col=l16
      f32x4 st[4];
#pragma unroll
      for (int jt = 0; jt < 4; ++jt) {
        bf16x8 kf[4];
#pragma unroll
        for (int t = 0; t < 4; ++t) {
          int pos = (t * 4 + quad) ^ l16;
          kf[t] = *(const bf16x8*)(sK + (jt * 16 + l16) * HD_ + pos * 8);
        }
        f32x4 a2 = (f32x4)0.0f;
#pragma unroll
        for (int t = 0; t < 4; ++t) a2 = mfma16(kf[t], qf[t], a2);
        st[jt] = a2;
      }

      // causal mask only where the tile crosses this wave's diagonal
      if (kk0 + 63 > wq_abs) {
        int qcol = wq_abs + l16;
#pragma unroll
        for (int jt = 0; jt < 4; ++jt)
#pragma unroll
          for (int r = 0; r < 4; ++r) {
            int key = kk0 + jt * 16 + quad * 4 + r;
            if (key > qcol) st[jt][r] = NEG_SENTINEL;
          }
      }

      // online softmax (base-2): in-lane tree + 2 shuffles per reduction
      float mx = NEG_SENTINEL;
#pragma unroll
      for (int jt = 0; jt < 4; ++jt)
#pragma unroll
        for (int r = 0; r < 4; ++r) mx = fmaxf(mx, st[jt][r]);
      mx = fmaxf(mx, __shfl_xor(mx, 16, 64));
      mx = fmaxf(mx, __shfl_xor(mx, 32, 64));
      float m_new = fmaxf(m_col, mx);
      float alpha = exp2f(m_col - m_new);
      float ts = 0.0f;
#pragma unroll
      for (int jt = 0; jt < 4; ++jt) {
        bf16x4 pk;
#pragma unroll
        for (int r = 0; r < 4; ++r) {
          float p = exp2f(st[jt][r] - m_new);
          ts += p;
          pk[r] = (bf16)p;
        }
        *(bf16x4*)(sP + (wq + l16) * SPS + jt * 16 + quad * 4) = pk;
      }
      ts += __shfl_xor(ts, 16, 64);
      ts += __shfl_xor(ts, 32, 64);
      l_col = l_col * alpha + ts;
      m_col = m_new;
#pragma unroll
      for (int r = 0; r < 4; ++r) {
        float av = __shfl(alpha, quad * 4 + r, 64);
#pragma unroll
        for (int jd = 0; jd < 8; ++jd) o_acc[jd][r] *= av;
      }
      // sP rows are wave-private: same-wave LDS RAW needs no barrier.

      // O += P V  (two 32-key steps)
#pragma unroll
      for (int ks = 0; ks < 2; ++ks) {
        bf16x8 pf = *(const bf16x8*)(sP + (wq + l16) * SPS + ks * 32 + quad * 8);
#pragma unroll
        for (int jd = 0; jd < 8; ++jd) {
          int pos = (ks * 4 + quad) ^ (l16 & 7);
          bf16x8 vf = *(const bf16x8*)(sVT + (jd * 16 + l16) * ABK + pos * 8);
          o_acc[jd] = mfma16(pf, vf, o_acc[jd]);
        }
      }
    }
  }

  // epilogue: fetch denom from q-col lanes, store ctx (dense stride D_)
#pragma unroll
  for (int r = 0; r < 4; ++r) {
    float lv = __shfl(l_col, quad * 4 + r, 64);
    float inv_l = 1.0f / lv;
    int row = wq_abs + quad * 4 + r;
#pragma unroll
    for (int jd = 0; jd < 8; ++jd) {
      int colo = jd * 16 + l16;
      Oh[(size_t)row * D_ + colo] = (bf16)(o_acc[jd][r] * inv_l);
    }
  }
}

// ---------------------------------------------------------------------------
extern "C" void kernel_launch(void* const* d_in, const int* in_sizes, int n_in,
                              void* d_out, int out_size, void* d_ws, size_t ws_size,
                              hipStream_t stream) {
  const float* x    = (const float*)d_in[0];
  const float* Wq   = (const float*)d_in[1];
  const float* Wk   = (const float*)d_in[2];
  const float* Wv   = (const float*)d_in[3];
  const float* Wo   = (const float*)d_in[4];
  const float* cosT = (const float*)d_in[5];
  const float* sinT = (const float*)d_in[6];
  float* out = (float*)d_out;

  const size_t NE = (size_t)B_ * S_ * D_;   // 8,388,608
  const size_t WE = (size_t)D_ * D_;        // 4,194,304
  const int M = B_ * S_;
  const int cvtX = (int)(NE / 1024);
  const int cvtW = (int)(WE / 1024);
  const int ropeG = (B_ * S_ * H_ * 8) / 256;   // 2048 blocks

  if (ws_size >= (size_t)92274688) {
    // ---- fused-QKV path (88 MB): QKV(48) | xb(16) | Wqkv->ctx+Wo_b(24) ----
    bf16* QKV   = (bf16*)d_ws;              // (4096, 6144) row-major
    bf16* xb    = QKV + (size_t)M * 6144;
    bf16* Wqkv  = xb + NE;
    bf16* ctx   = Wqkv;                     // reuse after QKV GEMM
    bf16* Wob   = Wqkv + 2 * WE;
    bf16* Vt    = xb;                       // reuse after QKV GEMM

    // fused cvt: x + Wq + Wk + Wv in one launch (Wo later: aliases Wv slot)
    cvt_qkvx<<<8192 + 3 * 4096, 256, 0, stream>>>(x, xb, Wq, Wk, Wv, Wqkv);
    gemm_xwt<bf16><<<dim3(48, 32), 256, 0, stream>>>(xb, Wqkv, QKV, M, 3 * D_, D_, 3 * D_);
    rope_qk<<<ropeG, 256, 0, stream>>>(QKV, QKV + D_, cosT, sinT, 3 * D_);
    transpose_v<<<dim3(32, 2, 32), 256, 0, stream>>>(QKV + 2 * D_, Vt, 3 * D_);
    attn_fwd<<<512, 512, 0, stream>>>(QKV, QKV + D_, Vt, ctx, 3 * D_);
    cvt_f32_bf16<<<cvtW, 256, 0, stream>>>(Wo, Wob);
    gemm_xwt<float><<<dim3(16, 32), 256, 0, stream>>>(ctx, Wob, out, M, D_, D_, D_);
  } else {
    // ---- fallback (72 MB): separate GEMMs, same attn ----
    bf16* Qb    = (bf16*)d_ws;
    bf16* Kb    = Qb + NE;
    bf16* Vb    = Kb + NE;
    bf16* Cb    = Vb + NE;                  // bf16(x) -> later Vt
    bf16* Wslot = Cb + NE;

    cvt_f32_bf16<<<cvtX, 256, 0, stream>>>(x, Cb);
    cvt_f32_bf16<<<cvtW, 256, 0, stream>>>(Wq, Wslot);
    gemm_xwt<bf16><<<dim3(16, 32), 256, 0, stream>>>(Cb, Wslot, Qb, M, D_, D_, D_);
    cvt_f32_bf16<<<cvtW, 256, 0, stream>>>(Wk, Wslot);
    gemm_xwt<bf16><<<dim3(16, 32), 256, 0, stream>>>(Cb, Wslot, Kb, M, D_, D_, D_);
    cvt_f32_bf16<<<cvtW, 256, 0, stream>>>(Wv, Wslot);
    gemm_xwt<bf16><<<dim3(16, 32), 256, 0, stream>>>(Cb, Wslot, Vb, M, D_, D_, D_);
    rope_qk<<<ropeG, 256, 0, stream>>>(Qb, Kb, cosT, sinT, D_);
    transpose_v<<<dim3(32, 2, 32), 256, 0, stream>>>(Vb, Cb, D_);
    attn_fwd<<<512, 512, 0, stream>>>(Qb, Kb, Cb, Vb, D_);
    cvt_f32_bf16<<<cvtW, 256, 0, stream>>>(Wo, Wslot);
    gemm_xwt<float><<<dim3(16, 32), 256, 0, stream>>>(Vb, Wslot, out, M, D_, D_, D_);
  }
}

// Round 9
// 379.848 us; speedup vs baseline: 1.4597x; 1.0755x over previous
//
#include <hip/hip_runtime.h>
#include <cstdint>
#include <cmath>

#define B_ 2
#define S_ 2048
#define D_ 2048
#define H_ 16
#define HD_ 128

#define NEG_SENTINEL -1.0e30f

typedef __bf16 bf16;
typedef __attribute__((ext_vector_type(4))) __bf16 bf16x4;
typedef __attribute__((ext_vector_type(8))) __bf16 bf16x8;
typedef __attribute__((ext_vector_type(4))) float f32x4;

__device__ __forceinline__ void gload_lds16(const void* g, void* l) {
  __builtin_amdgcn_global_load_lds(
      (const __attribute__((address_space(1))) unsigned int*)g,
      (__attribute__((address_space(3))) unsigned int*)l, 16, 0, 0);
}

__device__ __forceinline__ f32x4 mfma16(bf16x8 a, bf16x8 b, f32x4 c) {
  return __builtin_amdgcn_mfma_f32_16x16x32_bf16(a, b, c, 0, 0, 0);
}

__device__ __forceinline__ void wg_barrier() {
  asm volatile("" ::: "memory");
  __builtin_amdgcn_s_barrier();
  asm volatile("" ::: "memory");
}

#define AVM0() asm volatile("s_waitcnt vmcnt(0)" ::: "memory")

// ---------------------------------------------------------------------------
// fp32 -> bf16 convert. One thread = 4 elements. (fallback path)
// ---------------------------------------------------------------------------
__global__ __launch_bounds__(256) void cvt_f32_bf16(
    const float* __restrict__ in, bf16* __restrict__ out)
{
  int i = blockIdx.x * 256 + threadIdx.x;
  f32x4 v = ((const f32x4*)in)[i];
  bf16x4 o;
#pragma unroll
  for (int j = 0; j < 4; ++j) o[j] = (bf16)v[j];
  ((bf16x4*)out)[i] = o;
}

// ---------------------------------------------------------------------------
// Fused front-end convert: x (8192 blocks) + Wq/Wk/Wv (4096 blocks each)
// in ONE launch. Wo excluded (its slot aliases Wv until QKV GEMM is done).
// ---------------------------------------------------------------------------
__global__ __launch_bounds__(256) void cvt_qkvx(
    const float* __restrict__ x, bf16* __restrict__ xb,
    const float* __restrict__ wq, const float* __restrict__ wk,
    const float* __restrict__ wv, bf16* __restrict__ wout)
{
  int b = (int)blockIdx.x;
  const float* in; bf16* out; int base;
  if (b < 8192)      { in = x;  out = xb; base = b; }
  else {
    int r = b - 8192; int j = r >> 12; base = r & 4095;
    if (j == 0)      { in = wq; out = wout; }
    else if (j == 1) { in = wk; out = wout + 4194304; }
    else             { in = wv; out = wout + 8388608; }
  }
  int i = base * 256 + threadIdx.x;
  f32x4 v = ((const f32x4*)in)[i];
  bf16x4 o;
#pragma unroll
  for (int t2 = 0; t2 < 4; ++t2) o[t2] = (bf16)v[t2];
  ((bf16x4*)out)[i] = o;
}

// ---------------------------------------------------------------------------
// GEMM (verified, ~897 TF): 128x128 tile, BK=64.
// R1-R4 post-mortem: 256-class pipelined tiles hit 1109 TF intrinsic but
// grid quantization eats the gain; legacy balanced grids win end-to-end.
// ---------------------------------------------------------------------------
#define GTM 128
#define GTN 128
#define GBK 64

template <typename OT>
__global__ __launch_bounds__(256) void gemm_xwt(
    const bf16* __restrict__ A, const bf16* __restrict__ W, OT* __restrict__ C,
    int M, int N, int K, int ldc)
{
  __shared__ bf16 sA[GTM * GBK];
  __shared__ bf16 sB[GTN * GBK];
  const int tid  = threadIdx.x;
  const int wave = tid >> 6, lane = tid & 63;
  const int quad = lane >> 4, l16 = lane & 15;
  const int tm = blockIdx.y * GTM;
  const int tn = blockIdx.x * GTN;
  const int wm = (wave >> 1) * 64, wn = (wave & 1) * 64;

  f32x4 acc[4][4];
#pragma unroll
  for (int i = 0; i < 4; ++i)
#pragma unroll
    for (int j = 0; j < 4; ++j) acc[i][j] = (f32x4)0.0f;

  for (int k0 = 0; k0 < K; k0 += GBK) {
    __syncthreads();
#pragma unroll
    for (int g = 0; g < 4; ++g) {
      int gb  = (g * 4 + wave) * 64;
      int p   = gb + lane;
      int row = p >> 3, pos = p & 7;
      int cc  = pos ^ (row & 7);
      gload_lds16(A + (size_t)(tm + row) * K + k0 + cc * 8, (char*)sA + (size_t)gb * 16);
      gload_lds16(W + (size_t)(tn + row) * K + k0 + cc * 8, (char*)sB + (size_t)gb * 16);
    }
    __syncthreads();

#pragma unroll
    for (int t = 0; t < 2; ++t) {
      bf16x8 af[4], bfr[4];
#pragma unroll
      for (int i = 0; i < 4; ++i) {
        int rowa = wm + i * 16 + l16;
        int posa = (t * 4 + quad) ^ (rowa & 7);
        af[i] = *(const bf16x8*)(sA + rowa * GBK + posa * 8);
        int rowb = wn + i * 16 + l16;
        int posb = (t * 4 + quad) ^ (rowb & 7);
        bfr[i] = *(const bf16x8*)(sB + rowb * GBK + posb * 8);
      }
#pragma unroll
      for (int i = 0; i < 4; ++i)
#pragma unroll
        for (int j = 0; j < 4; ++j)
          acc[i][j] = mfma16(af[i], bfr[j], acc[i][j]);
    }
  }

#pragma unroll
  for (int i = 0; i < 4; ++i)
#pragma unroll
    for (int r = 0; r < 4; ++r) {
      int row = tm + wm + i * 16 + quad * 4 + r;
#pragma unroll
      for (int j = 0; j < 4; ++j) {
        int col = tn + wn + j * 16 + l16;
        C[(size_t)row * ldc + col] = (OT)acc[i][j][r];
      }
    }
}

// ---------------------------------------------------------------------------
// RoPE in-place, vectorized: one thread = 8 paired lanes (16 bf16).
// Same per-element math/rounding as scalar -> bit-identical.
// ---------------------------------------------------------------------------
__global__ __launch_bounds__(256) void rope_qk(
    bf16* __restrict__ Q, bf16* __restrict__ Kk,
    const float* __restrict__ cosT, const float* __restrict__ sinT, int rs)
{
  const float kappa = 0.08838834764831845f * 1.4426950408889634f;
  int t  = blockIdx.x * 256 + threadIdx.x;     // B*S*H*8 threads
  int d0 = (t & 7) * 8;
  int h  = (t >> 3) & (H_ - 1);
  int s  = (t >> 7) & (S_ - 1);
  int b  = t >> 18;
  size_t base = ((size_t)(b * S_ + s)) * rs + (size_t)h * HD_;

  const float* cl = cosT + s * HD_ + d0;
  const float* sl = sinT + s * HD_ + d0;

  bf16x8 ql = *(const bf16x8*)(Q + base + d0);
  bf16x8 qh = *(const bf16x8*)(Q + base + 64 + d0);
  bf16x8 kl = *(const bf16x8*)(Kk + base + d0);
  bf16x8 kh = *(const bf16x8*)(Kk + base + 64 + d0);

  bf16x8 qlo, qho, klo, kho;
#pragma unroll
  for (int i = 0; i < 8; ++i) {
    float c1 = cl[i], s1 = sl[i];
    float c2 = cl[64 + i], s2 = sl[64 + i];
    float x1 = (float)ql[i], x2 = (float)qh[i];
    qlo[i] = (bf16)((x1 * c1 - x2 * s1) * kappa);
    qho[i] = (bf16)((x2 * c2 + x1 * s2) * kappa);
    float y1 = (float)kl[i], y2 = (float)kh[i];
    klo[i] = (bf16)(y1 * c1 - y2 * s1);
    kho[i] = (bf16)(y2 * c2 + y1 * s2);
  }
  *(bf16x8*)(Q + base + d0)       = qlo;
  *(bf16x8*)(Q + base + 64 + d0)  = qho;
  *(bf16x8*)(Kk + base + d0)      = klo;
  *(bf16x8*)(Kk + base + 64 + d0) = kho;
}

// ---------------------------------------------------------------------------
// V transpose: V[b][s][...] (row stride rs) -> Vt[(b*H+h)*128+d][s].
// ---------------------------------------------------------------------------
__global__ __launch_bounds__(256) void transpose_v(
    const bf16* __restrict__ V, bf16* __restrict__ Vt, int rs)
{
  __shared__ bf16 sT[64 * 72];
  const int tid = threadIdx.x;
  const int si = blockIdx.x;
  const int di = blockIdx.y;
  const int bh = blockIdx.z;
  const int b  = bh >> 4, h = bh & 15;

  const bf16* src = V + (size_t)b * S_ * rs + (size_t)h * HD_ + di * 64;
  bf16*       dst = Vt + ((size_t)bh * HD_ + di * 64) * S_ + si * 64;

#pragma unroll
  for (int half = 0; half < 2; ++half) {
    int r  = half * 32 + (tid >> 3);
    int c0 = (tid & 7) * 8;
    bf16x8 v = *(const bf16x8*)(src + (size_t)(si * 64 + r) * rs + c0);
    *(bf16x8*)(sT + r * 72 + c0) = v;
  }
  __syncthreads();
#pragma unroll
  for (int half = 0; half < 2; ++half) {
    int dr = half * 32 + (tid >> 3);
    int c0 = (tid & 7) * 8;
    bf16x8 o;
#pragma unroll
    for (int j = 0; j < 8; ++j) o[j] = sT[(c0 + j) * 72 + dr];
    *(bf16x8*)(dst + (size_t)dr * S_ + c0) = o;
  }
}

// ---------------------------------------------------------------------------
// Flash attention fwd, causal. R9 = balanced pairs + 8 waves + K/V dbuf.
// R8 post-mortem: 512 variable-length blocks all start at t=0 and the two
// blocks sharing a CU get the SAME qt (round-robin XCD dispatch) -> CU work
// spans 4..64 iter-units, makespan ~1.9x ideal. Fix: every block processes
// the pair (qt, 15-qt) sequentially = exactly 34 iterations, zero imbalance
// (R0's design, at 8 waves). Grid 256 = 1 block/CU.
// Per k-tile: {issue stage(t+1 -> buf^1); compute(buf); vmcnt(0); barrier}
// -> the ~300-500cy L2 drain that used to serialize before compute now
// hides under it (R5's dbuf without its occupancy loss: only 1 block fits
// at 8 waves regardless, so the 82KB LDS is free).
// Ledger: buf^1 last read in iter kt-1 (sealed by its end barrier); staged
// data retired by this iter's vmcnt(0) before swap. Seg boundary: final
// barrier of seg0 seals both buffers before seg1's prologue.
// Compute body byte-identical to R8 -> same numerics.
// Decode: 256 = 8 XCD x {8 pairx x 4 colhi}; col = low3 + colhi*8 keeps
// 4 head-cols per XCD (K/V working set 4MB = per-XCD L2).
// ---------------------------------------------------------------------------
#define ABK 64
#define SPS 72

#define AK_STAGE(kt_, b_) do { \
    int kk_ = (kt_) * ABK; \
    _Pragma("unroll") \
    for (int g_ = 0; g_ < 2; ++g_) { \
      int p_   = g_ * 512 + tid; \
      int row_ = p_ >> 4, pos_ = p_ & 15; \
      int cc_  = pos_ ^ (row_ & 15); \
      gload_lds16(Kh + (size_t)(kk_ + row_) * rs + cc_ * 8, \
                  (char*)sK + (b_) * 16384 + (size_t)p_ * 16); \
    } } while (0)

#define AV_STAGE(kt_, b_) do { \
    int kk_ = (kt_) * ABK; \
    _Pragma("unroll") \
    for (int g_ = 0; g_ < 2; ++g_) { \
      int p_  = g_ * 512 + tid; \
      int d_  = p_ >> 3, pos_ = p_ & 7; \
      int cc_ = pos_ ^ (d_ & 7); \
      gload_lds16(Vth + (size_t)d_ * S_ + kk_ + cc_ * 8, \
                  (char*)sVT + (b_) * 16384 + (size_t)p_ * 16); \
    } } while (0)

__global__ __launch_bounds__(512) void attn_fwd(
    const bf16* __restrict__ Q, const bf16* __restrict__ K,
    const bf16* __restrict__ Vt, bf16* __restrict__ O, int rs)
{
  __shared__ bf16 sK[2 * ABK * HD_];   // 32 KB (dbuf)
  __shared__ bf16 sVT[2 * HD_ * ABK];  // 32 KB (dbuf)
  __shared__ bf16 sP[128 * SPS];       // 18 KB  (total 82.4 KB, 1 block/CU)

  const int tid  = threadIdx.x;
  const int wave = tid >> 6, lane = tid & 63;
  const int quad = lane >> 4, l16 = lane & 15;

  // decode: 256 = 8 (XCD) x 8 (pairx) x 4 (colhi)
  const int lin   = (int)blockIdx.x;
  const int low3  = lin & 7;
  const int rest  = lin >> 3;          // 0..31
  const int pairx = rest & 7;          // 0..7
  const int colhi = rest >> 3;         // 0..3
  const int col   = low3 + (colhi << 3);
  const int b = col >> 4, h = col & 15;

  const bf16* Qh  = Q + (size_t)b * S_ * rs + (size_t)h * HD_;
  const bf16* Kh  = K + (size_t)b * S_ * rs + (size_t)h * HD_;
  const bf16* Vth = Vt + ((size_t)(b * H_ + h) * HD_) * S_;
  bf16*       Oh  = O + (size_t)b * S_ * D_ + (size_t)h * HD_;

  const int wq = wave * 16;            // 0..112

  // balanced pair: qt + (15-qt) -> (2qt+2)+(32-2qt) = 34 iters per block
#pragma unroll 1
  for (int seg = 0; seg < 2; ++seg) {
    const int qt = seg == 0 ? pairx : 15 - pairx;
    const int q0 = qt * 128;
    const int wq_abs = q0 + wq;

    // Q fragments (B operand; layout [n=l16][k=quad*8+j])
    bf16x8 qf[4];
    {
      const bf16* rp = Qh + (size_t)(wq_abs + l16) * rs + quad * 8;
#pragma unroll
      for (int t = 0; t < 4; ++t) qf[t] = *(const bf16x8*)(rp + t * 32);
    }

    f32x4 o_acc[8];
#pragma unroll
    for (int j = 0; j < 8; ++j) o_acc[j] = (f32x4)0.0f;
    float m_col = NEG_SENTINEL;
    float l_col = 0.0f;

    const int nkt = 2 * qt + 2;

    // prologue: stage tile 0 into buf 0 (both buffers sealed by the
    // barrier ending the previous segment / kernel entry)
    AK_STAGE(0, 0);
    AV_STAGE(0, 0);
    AVM0();
    wg_barrier();

    int cur = 0;
#pragma unroll 1
    for (int kt = 0; kt < nkt; ++kt) {
      const int kk0 = kt * ABK;
      const bf16* sKc = sK + cur * (ABK * HD_);
      const bf16* sVc = sVT + cur * (HD_ * ABK);

      // issue next tile's staging into the other buffer; its latency
      // hides under this tile's compute, retired by this iter's vmcnt(0)
      if (kt + 1 < nkt) {
        AK_STAGE(kt + 1, cur ^ 1);
        AV_STAGE(kt + 1, cur ^ 1);
      }

      // waves whose 16 q-rows are entirely below this key tile skip compute
      if (kk0 <= wq_abs + 15) {
        // S^T = K Q^T : lane holds key=(jt*16+quad*4+r), q-col=l16
        f32x4 st[4];
#pragma unroll
        for (int jt = 0; jt < 4; ++jt) {
          bf16x8 kf[4];
#pragma unroll
          for (int t = 0; t < 4; ++t) {
            int pos = (t * 4 + quad) ^ l16;
            kf[t] = *(const bf16x8*)(sKc + (jt * 16 + l16) * HD_ + pos * 8);
          }
          f32x4 a2 = (f32x4)0.0f;
#pragma unroll
          for (int t = 0; t < 4; ++t) a2 = mfma16(kf[t], qf[t], a2);
          st[jt] = a2;
        }

        // causal mask only where the tile crosses this wave's diagonal
        if (kk0 + 63 > wq_abs) {
          int qcol = wq_abs + l16;
#pragma unroll
          for (int jt = 0; jt < 4; ++jt)
#pragma unroll
            for (int r = 0; r < 4; ++r) {
              int key = kk0 + jt * 16 + quad * 4 + r;
              if (key > qcol) st[jt][r] = NEG_SENTINEL;
            }
        }

        // online softmax (base-2): in-lane tree + 2 shuffles per reduction
        float mx = NEG_SENTINEL;
#pragma unroll
        for (int jt = 0; jt < 4; ++jt)
#pragma unroll
          for (int r = 0; r < 4; ++r) mx = fmaxf(mx, st[jt][r]);
        mx = fmaxf(mx, __shfl_xor(mx, 16, 64));
        mx = fmaxf(mx, __shfl_xor(mx, 32, 64));
        float m_new = fmaxf(m_col, mx);
        float alpha = exp2f(m_col - m_new);
        float ts = 0.0f;
#pragma unroll
        for (int jt = 0; jt < 4; ++jt) {
          bf16x4 pk;
#pragma unroll
          for (int r = 0; r < 4; ++r) {
            float p = exp2f(st[jt][r] - m_new);
            ts += p;
            pk[r] = (bf16)p;
          }
          *(bf16x4*)(sP + (wq + l16) * SPS + jt * 16 + quad * 4) = pk;
        }
        ts += __shfl_xor(ts, 16, 64);
        ts += __shfl_xor(ts, 32, 64);
        l_col = l_col * alpha + ts;
        m_col = m_new;
#pragma unroll
        for (int r = 0; r < 4; ++r) {
          float av = __shfl(alpha, quad * 4 + r, 64);
#pragma unroll
          for (int jd = 0; jd < 8; ++jd) o_acc[jd][r] *= av;
        }
        // sP rows are wave-private: same-wave LDS RAW needs no barrier.

        // O += P V  (two 32-key steps)
#pragma unroll
        for (int ks = 0; ks < 2; ++ks) {
          bf16x8 pf = *(const bf16x8*)(sP + (wq + l16) * SPS + ks * 32 + quad * 8);
#pragma unroll
          for (int jd = 0; jd < 8; ++jd) {
            int pos = (ks * 4 + quad) ^ (l16 & 7);
            bf16x8 vf = *(const bf16x8*)(sVc + (jd * 16 + l16) * ABK + pos * 8);
            o_acc[jd] = mfma16(pf, vf, o_acc[jd]);
          }
        }
      }

      // retire next-tile staging (mostly drained: full compute elapsed
      // since issue); barrier seals buffer reuse for next iteration
      AVM0();
      wg_barrier();
      cur ^= 1;
    }

    // epilogue: fetch denom from q-col lanes, store ctx (dense stride D_)
#pragma unroll
    for (int r = 0; r < 4; ++r) {
      float lv = __shfl(l_col, quad * 4 + r, 64);
      float inv_l = 1.0f / lv;
      int row = wq_abs + quad * 4 + r;
#pragma unroll
      for (int jd = 0; jd < 8; ++jd) {
        int colo = jd * 16 + l16;
        Oh[(size_t)row * D_ + colo] = (bf16)(o_acc[jd][r] * inv_l);
      }
    }
  }
}

// ---------------------------------------------------------------------------
extern "C" void kernel_launch(void* const* d_in, const int* in_sizes, int n_in,
                              void* d_out, int out_size, void* d_ws, size_t ws_size,
                              hipStream_t stream) {
  const float* x    = (const float*)d_in[0];
  const float* Wq   = (const float*)d_in[1];
  const float* Wk   = (const float*)d_in[2];
  const float* Wv   = (const float*)d_in[3];
  const float* Wo   = (const float*)d_in[4];
  const float* cosT = (const float*)d_in[5];
  const float* sinT = (const float*)d_in[6];
  float* out = (float*)d_out;

  const size_t NE = (size_t)B_ * S_ * D_;   // 8,388,608
  const size_t WE = (size_t)D_ * D_;        // 4,194,304
  const int M = B_ * S_;
  const int cvtX = (int)(NE / 1024);
  const int cvtW = (int)(WE / 1024);
  const int ropeG = (B_ * S_ * H_ * 8) / 256;   // 2048 blocks

  if (ws_size >= (size_t)92274688) {
    // ---- fused-QKV path (88 MB): QKV(48) | xb(16) | Wqkv->ctx+Wo_b(24) ----
    bf16* QKV   = (bf16*)d_ws;              // (4096, 6144) row-major
    bf16* xb    = QKV + (size_t)M * 6144;
    bf16* Wqkv  = xb + NE;
    bf16* ctx   = Wqkv;                     // reuse after QKV GEMM
    bf16* Wob   = Wqkv + 2 * WE;
    bf16* Vt    = xb;                       // reuse after QKV GEMM

    // fused cvt: x + Wq + Wk + Wv in one launch (Wo later: aliases Wv slot)
    cvt_qkvx<<<8192 + 3 * 4096, 256, 0, stream>>>(x, xb, Wq, Wk, Wv, Wqkv);
    gemm_xwt<bf16><<<dim3(48, 32), 256, 0, stream>>>(xb, Wqkv, QKV, M, 3 * D_, D_, 3 * D_);
    rope_qk<<<ropeG, 256, 0, stream>>>(QKV, QKV + D_, cosT, sinT, 3 * D_);
    transpose_v<<<dim3(32, 2, 32), 256, 0, stream>>>(QKV + 2 * D_, Vt, 3 * D_);
    attn_fwd<<<256, 512, 0, stream>>>(QKV, QKV + D_, Vt, ctx, 3 * D_);
    cvt_f32_bf16<<<cvtW, 256, 0, stream>>>(Wo, Wob);
    gemm_xwt<float><<<dim3(16, 32), 256, 0, stream>>>(ctx, Wob, out, M, D_, D_, D_);
  } else {
    // ---- fallback (72 MB): separate GEMMs, same attn ----
    bf16* Qb    = (bf16*)d_ws;
    bf16* Kb    = Qb + NE;
    bf16* Vb    = Kb + NE;
    bf16* Cb    = Vb + NE;                  // bf16(x) -> later Vt
    bf16* Wslot = Cb + NE;

    cvt_f32_bf16<<<cvtX, 256, 0, stream>>>(x, Cb);
    cvt_f32_bf16<<<cvtW, 256, 0, stream>>>(Wq, Wslot);
    gemm_xwt<bf16><<<dim3(16, 32), 256, 0, stream>>>(Cb, Wslot, Qb, M, D_, D_, D_);
    cvt_f32_bf16<<<cvtW, 256, 0, stream>>>(Wk, Wslot);
    gemm_xwt<bf16><<<dim3(16, 32), 256, 0, stream>>>(Cb, Wslot, Kb, M, D_, D_, D_);
    cvt_f32_bf16<<<cvtW, 256, 0, stream>>>(Wv, Wslot);
    gemm_xwt<bf16><<<dim3(16, 32), 256, 0, stream>>>(Cb, Wslot, Vb, M, D_, D_, D_);
    rope_qk<<<ropeG, 256, 0, stream>>>(Qb, Kb, cosT, sinT, D_);
    transpose_v<<<dim3(32, 2, 32), 256, 0, stream>>>(Vb, Cb, D_);
    attn_fwd<<<256, 512, 0, stream>>>(Qb, Kb, Cb, Vb, D_);
    cvt_f32_bf16<<<cvtW, 256, 0, stream>>>(Wo, Wslot);
    gemm_xwt<float><<<dim3(16, 32), 256, 0, stream>>>(Vb, Wslot, out, M, D_, D_, D_);
  }
}